// Round 7
// baseline (2597.506 us; speedup 1.0000x reference)
//
#include <hip/hip_runtime.h>
#include <cmath>

#define TT 64
#define BB 64
#define SS 512
#define AA 16
#define RR 64
#define HH 32
#define EPS 1e-6f

// ws layout in floats
#define WS_TR   0                         // transition [A][S][S] = 4194304
#define WS_AT   4194304                   // alpha_a transposed [T][A][B] = 65536
#define WS_PDF  (WS_AT + 65536)           // tau_pdf [32]
#define WS_X0   (WS_PDF + 32)             // sigma buf 0 [B][S] = 32768
#define WS_X1   (WS_X0 + 32768)           // sigma buf 1
#define WS_X2   (WS_X1 + 32768)           // sigma buf 2
#define WS_BAR  (WS_X2 + 32768)           // barrier region (1024 uints)
#define WS_G    (WS_BAR + 1024)           // G bufs: 3 x [64 n x 16 pad] = 3072

#define AGENT __HIP_MEMORY_SCOPE_AGENT

__device__ __forceinline__ float aload(const float* p) {
  return __hip_atomic_load(p, __ATOMIC_RELAXED, AGENT);
}
__device__ __forceinline__ void astore(float* p, float v) {
  __hip_atomic_store(p, v, __ATOMIC_RELAXED, AGENT);
}

// ---------------- transition
__global__ __launch_bounds__(256) void k_trans2(const float* __restrict__ u,
                                                const float* __restrict__ v,
                                                float* __restrict__ Tr) {
  int bx = blockIdx.x;
  int k = bx >> 5, ic = bx & 31, i0 = ic * 16;
  __shared__ float urot_s[16][68];
  __shared__ float ut_s[64][68];
  __shared__ float w_s[16][516];
  int tid = threadIdx.x;
  int lane = tid & 63, wv = tid >> 6;

  float vkm = v[k*RR + lane];
  float n2 = vkm * vkm;
  #pragma unroll
  for (int o = 32; o > 0; o >>= 1) n2 += __shfl_xor(n2, o, 64);

  #pragma unroll
  for (int r = 0; r < 4; r++) {
    int il = wv*4 + r;
    float um = u[(size_t)(i0 + il)*RR + lane];
    float dt = um * vkm;
    #pragma unroll
    for (int o = 32; o > 0; o >>= 1) dt += __shfl_xor(dt, o, 64);
    urot_s[il][lane] = um - (2.f * dt / n2) * vkm;
  }

  int il = tid >> 4, jl4 = (tid & 15) * 4;
  for (int jt = 0; jt < 8; jt++) {
    __syncthreads();
    #pragma unroll
    for (int q = 0; q < 4; q++) {
      int fi = q*256 + tid;
      int r = fi >> 4, c4 = (fi & 15) * 4;
      float4 uu = *(const float4*)(u + (size_t)(jt*64 + r)*RR + c4);
      ut_s[c4+0][r] = uu.x; ut_s[c4+1][r] = uu.y;
      ut_s[c4+2][r] = uu.z; ut_s[c4+3][r] = uu.w;
    }
    __syncthreads();
    float4 acc = {0.f, 0.f, 0.f, 0.f};
    #pragma unroll 8
    for (int m = 0; m < 64; m++) {
      float ur = urot_s[il][m];
      float4 uu = *(const float4*)&ut_s[m][jl4];
      acc.x = fmaf(ur, uu.x, acc.x);
      acc.y = fmaf(ur, uu.y, acc.y);
      acc.z = fmaf(ur, uu.z, acc.z);
      acc.w = fmaf(ur, uu.w, acc.w);
    }
    *(float4*)&w_s[il][jt*64 + jl4] = acc;
  }
  __syncthreads();

  #pragma unroll
  for (int r = 0; r < 4; r++) {
    int ir = wv*4 + r;
    float vals[8]; float mx = -1e30f;
    #pragma unroll
    for (int q = 0; q < 8; q++) { vals[q] = w_s[ir][q*64 + lane]; mx = fmaxf(mx, vals[q]); }
    #pragma unroll
    for (int o = 32; o > 0; o >>= 1) mx = fmaxf(mx, __shfl_xor(mx, o, 64));
    float sm = 0.f;
    #pragma unroll
    for (int q = 0; q < 8; q++) { vals[q] = expf(vals[q] - mx); sm += vals[q]; }
    #pragma unroll
    for (int o = 32; o > 0; o >>= 1) sm += __shfl_xor(sm, o, 64);
    float inv = 1.f / sm;
    #pragma unroll
    for (int q = 0; q < 8; q++)
      Tr[((size_t)k*SS + (i0 + ir))*SS + q*64 + lane] = vals[q] * inv;
  }
}

// ---------------- alpha_a transposed [T][A][B]
__global__ __launch_bounds__(256) void k_alpha_a(const float* __restrict__ lpu,
                                                 float* __restrict__ aT) {
  int idx = blockIdx.x*256 + threadIdx.x;
  int t = idx >> 6, n = idx & 63;
  const float* x = lpu + (size_t)idx * AA;
  float xs[AA]; float m = -1e30f;
  #pragma unroll
  for (int k = 0; k < AA; k++) { xs[k] = x[k]; m = fmaxf(m, xs[k]); }
  float s = 0.f;
  #pragma unroll
  for (int k = 0; k < AA; k++) { xs[k] = expf(xs[k]-m); s += xs[k]; }
  float inv = 1.f/s;
  #pragma unroll
  for (int k = 0; k < AA; k++) aT[t*(AA*BB) + k*BB + n] = xs[k]*inv;
}

// ---------------- Poisson pdf
__global__ void k_taupdf(const float* __restrict__ tau, float* __restrict__ pdf) {
  __shared__ float pl[HH]; __shared__ float ss;
  int tid = threadIdx.x;
  float rate = log1pf(expf(tau[0]));
  if (tid < HH) {
    float kk = (float)(tid+1);
    pl[tid] = expf(kk*logf(rate) - rate - lgammaf(kk+1.f));
  }
  __syncthreads();
  if (tid == 0) { float s = 0.f; for (int h = 0; h < HH; h++) s += pl[h]; ss = 1.f/s; }
  __syncthreads();
  if (tid < HH) pdf[tid] = pl[tid]*ss;
}

// ---------------- zero X1/X2, barrier, G bufs, alpha_pi
__global__ __launch_bounds__(256) void k_zero(float* __restrict__ X1,
                                              float* __restrict__ X2,
                                              unsigned* __restrict__ bar,
                                              float* __restrict__ G,
                                              float* __restrict__ alpha_pi) {
  int idx = blockIdx.x*256 + threadIdx.x;   // grid 256*256 = 65536
  if (idx < 32768) { X1[idx] = 0.f; X2[idx] = 0.f; }
  if (idx < 1024) bar[idx] = 0u;
  if (idx < 3072) G[idx] = 0.f;
  alpha_pi[idx] = 0.f;
}

// ---------------- persistent scan: 256 blocks x 512 thr, hierarchical barrier, fused G
// block = (jc = bx&15 [32 j], ic = bx>>4 [32 i]); group g = bx&7
__global__ __launch_bounds__(512) void k_scan(const float* __restrict__ Tr,
                                              const float* __restrict__ aT,
                                              const float* __restrict__ lpo,
                                              const float* __restrict__ b,
                                              float* __restrict__ X0,
                                              float* __restrict__ X1,
                                              float* __restrict__ X2,
                                              float* __restrict__ Gb,      // 3 x 1024
                                              float* __restrict__ alpha_b,
                                              unsigned* __restrict__ bar) {
  __shared__ float bel_s[32*68];    // padded stride 68: conflict-free GEMM reads
  __shared__ float a_s[16*64];
  __shared__ float invG_l[64];
  int tid = threadIdx.x, bx = blockIdx.x;
  int jc = bx & 15, ic = bx >> 4;
  int i0 = ic*32, j0 = jc*32;
  int g = bx & 7;
  unsigned* arr = bar + g*32;
  unsigned* gcnt = bar + 256;
  unsigned* rel = bar + 288 + g*32;

  for (int t = 0; t < TT; t++) {
    const float* Xr; float* Xw; float* Xz;
    const float* Gr; float* Gw; float* Gz;
    {
      int r = t % 3;
      if (r == 0)      { Xr = X0; Xw = X1; Xz = X2; Gr = Gb;      Gw = Gb+1024; Gz = Gb+2048; }
      else if (r == 1) { Xr = X1; Xw = X2; Xz = X0; Gr = Gb+1024; Gw = Gb+2048; Gz = Gb;      }
      else             { Xr = X2; Xw = X0; Xz = X1; Gr = Gb+2048; Gw = Gb;      Gz = Gb+1024; }
    }
    const float* lpoPrev = lpo + (size_t)(t-1)*BB*SS;

    // balanced zeroing of next-next buffers (untouched this step)
    if (tid < 128) astore(Xz + bx*128 + tid, 0.f);
    if (tid < 64)  astore(Gz + (size_t)tid*16, 0.f);   // redundant across blocks, harmless

    // invG from fused-G accumulator (written during step t-1)
    if (t > 0 && tid < 64) invG_l[tid] = 1.f / aload(Gr + (size_t)tid*16);
    __syncthreads();

    // stage bel_s slice (+ alpha_b[t-1] on diagonal blocks) and a_s
    if (t == 0) {
      #pragma unroll
      for (int q = 0; q < 4; q++) {
        int idx = q*512 + tid;
        int nn = idx >> 5, il = idx & 31;
        bel_s[il*68 + nn] = b[(size_t)nn*SS + i0 + il];
      }
    } else {
      #pragma unroll
      for (int q = 0; q < 4; q++) {
        int idx = q*512 + tid;
        int nn = idx >> 5, il = idx & 31;
        size_t off = (size_t)nn*SS + i0 + il;
        float val = (aload(Xr + off) + EPS) * expf(lpoPrev[off]) * invG_l[nn];
        bel_s[il*68 + nn] = val;
        if (ic == jc) alpha_b[((size_t)(t-1)*BB + nn)*SS + i0 + il] = val;  // plain store
      }
    }
    if (tid < 256) *(float4*)&a_s[tid*4] = *(const float4*)(aT + (size_t)t*1024 + tid*4);
    __syncthreads();

    // GEMM: thread (jq, ii, nq): 4 j x 4 i(io) x 16 k x 8 n
    int jq = tid & 7, ii = (tid >> 3) & 7, nq = tid >> 6;
    int n0 = nq*8;
    float4 acc[8];
    #pragma unroll
    for (int m = 0; m < 8; m++) acc[m] = make_float4(0.f, 0.f, 0.f, 0.f);
    const float* TrBase = Tr + (size_t)(i0 + ii)*SS + j0 + jq*4;

    for (int kb = 0; kb < 4; kb++) {
      float af[4][8];
      #pragma unroll
      for (int kk = 0; kk < 4; kk++) {
        *(float4*)&af[kk][0] = *(float4*)&a_s[(kb*4+kk)*64 + n0];
        *(float4*)&af[kk][4] = *(float4*)&a_s[(kb*4+kk)*64 + n0 + 4];
      }
      #pragma unroll
      for (int io = 0; io < 4; io++) {
        float bf[8];
        *(float4*)&bf[0] = *(float4*)&bel_s[(io*8+ii)*68 + n0];
        *(float4*)&bf[4] = *(float4*)&bel_s[(io*8+ii)*68 + n0 + 4];
        #pragma unroll
        for (int kk = 0; kk < 4; kk++) {
          float4 tv = *(const float4*)(TrBase + ((size_t)(kb*4+kk)*SS + io*8)*SS);
          #pragma unroll
          for (int m = 0; m < 8; m++) {
            float w = af[kk][m] * bf[m];
            acc[m].x = fmaf(w, tv.x, acc[m].x);
            acc[m].y = fmaf(w, tv.y, acc[m].y);
            acc[m].z = fmaf(w, tv.z, acc[m].z);
            acc[m].w = fmaf(w, tv.w, acc[m].w);
          }
        }
      }
    }

    // ii-reduce
    #pragma unroll
    for (int m = 0; m < 8; m++) {
      #pragma unroll
      for (int o = 8; o <= 32; o <<= 1) {
        acc[m].x += __shfl_xor(acc[m].x, o, 64);
        acc[m].y += __shfl_xor(acc[m].y, o, 64);
        acc[m].z += __shfl_xor(acc[m].z, o, 64);
        acc[m].w += __shfl_xor(acc[m].w, o, 64);
      }
    }
    // epilogue: Xw atomics + fused G contribution (uses lpo[t])
    if (ii == 0) {
      const float* lpoT = lpo + (size_t)t*BB*SS;
      float gpart[8];
      #pragma unroll
      for (int m = 0; m < 8; m++) {
        float* dst = Xw + (size_t)(n0+m)*SS + j0 + jq*4;
        atomicAdd(dst+0, acc[m].x);
        atomicAdd(dst+1, acc[m].y);
        atomicAdd(dst+2, acc[m].z);
        atomicAdd(dst+3, acc[m].w);
        float4 l4 = *(const float4*)(lpoT + (size_t)(n0+m)*SS + j0 + jq*4);
        float4 e4;
        e4.x = expf(l4.x); e4.y = expf(l4.y); e4.z = expf(l4.z); e4.w = expf(l4.w);
        float gp = acc[m].x*e4.x + acc[m].y*e4.y + acc[m].z*e4.z + acc[m].w*e4.w;
        if (ic == 0) gp += EPS * (e4.x + e4.y + e4.z + e4.w);
        gp += __shfl_xor(gp, 1, 64);
        gp += __shfl_xor(gp, 2, 64);
        gp += __shfl_xor(gp, 4, 64);
        gpart[m] = gp;
      }
      if (jq == 0) {
        #pragma unroll
        for (int m = 0; m < 8; m++)
          atomicAdd(Gw + (size_t)(n0+m)*16, gpart[m]);
      }
    }

    // hierarchical barrier, epoch t+1
    __syncthreads();
    if (tid == 0) {
      unsigned e = (unsigned)(t + 1);
      unsigned np = __hip_atomic_fetch_add(arr, 1u, __ATOMIC_RELEASE, AGENT);
      if (np == e*32u - 1u) {
        unsigned gp2 = __hip_atomic_fetch_add(gcnt, 1u, __ATOMIC_RELEASE, AGENT);
        if (gp2 == e*8u - 1u) {
          #pragma unroll
          for (int g2 = 0; g2 < 8; g2++)
            __hip_atomic_store(bar + 288 + g2*32, e, __ATOMIC_RELAXED, AGENT);
        }
      }
      while (__hip_atomic_load(rel, __ATOMIC_RELAXED, AGENT) < e)
        __builtin_amdgcn_s_sleep(1);
      __atomic_signal_fence(__ATOMIC_ACQUIRE);
    }
    __syncthreads();
  }
}

// ---------------- final belief (t=63) from X1
__global__ __launch_bounds__(512) void k_lastbel(const float* __restrict__ X,
                                                 const float* __restrict__ lpo,
                                                 float* __restrict__ alpha_b) {
  __shared__ float red[512];
  int n = blockIdx.x, j = threadIdx.x;
  size_t off = (size_t)n*SS + j;
  float g = (X[off] + EPS) * expf(lpo[((size_t)63*BB + n)*SS + j]);
  red[j] = g; __syncthreads();
  for (int s = 256; s > 0; s >>= 1) { if (j < s) red[j] += red[j+s]; __syncthreads(); }
  float inv = 1.f / red[0];
  alpha_b[((size_t)63*BB + n)*SS + j] = g * inv;
}

// ---------------- plan(): 512 blocks (n x hk-eighth) x 256 thr
__global__ __launch_bounds__(256) void k_pi(const float* __restrict__ alpha_b,
                                            const float* __restrict__ value,
                                            const float* __restrict__ pdf,
                                            float* __restrict__ alpha_pi) {
  __shared__ float Ab_l[64][132];
  __shared__ float lg[64][68];
  __shared__ float pdf_l[HH];
  int tid = threadIdx.x, bx = blockIdx.x;
  int n = bx >> 3, e = bx & 7;
  if (tid < HH) pdf_l[tid] = pdf[tid];
  int hkg = tid >> 3, tg = tid & 7;
  int hk0 = e*64 + hkg*2;
  const float* V0 = value + (((size_t)(hk0    >> 4)*BB + n)*AA + (hk0     & 15))*SS;
  const float* V1 = value + (((size_t)((hk0+1) >> 4)*BB + n)*AA + ((hk0+1) & 15))*SS;

  float4 a0[8], a1[8];
  #pragma unroll
  for (int m = 0; m < 8; m++) { a0[m] = make_float4(0,0,0,0); a1[m] = make_float4(0,0,0,0); }

  for (int it = 0; it < 4; it++) {
    __syncthreads();
    #pragma unroll
    for (int q = 0; q < 8; q++) {
      int idx = q*256 + tid;
      int tt = idx >> 5, il4 = (idx & 31)*4;
      float4 ab = *(const float4*)(alpha_b + ((size_t)tt*BB + n)*SS + it*128 + il4);
      *(float4*)&Ab_l[tt][il4] = ab;
    }
    __syncthreads();
    #pragma unroll 4
    for (int iq = 0; iq < 32; iq++) {
      float4 v0 = *(const float4*)(V0 + it*128 + iq*4);
      float4 v1 = *(const float4*)(V1 + it*128 + iq*4);
      #pragma unroll
      for (int tt = 0; tt < 8; tt++) {
        float4 ab = *(const float4*)&Ab_l[tt*8 + tg][iq*4];
        a0[tt].x = fmaf(ab.x, v0.x, a0[tt].x);
        a0[tt].y = fmaf(ab.y, v0.y, a0[tt].y);
        a0[tt].z = fmaf(ab.z, v0.z, a0[tt].z);
        a0[tt].w = fmaf(ab.w, v0.w, a0[tt].w);
        a1[tt].x = fmaf(ab.x, v1.x, a1[tt].x);
        a1[tt].y = fmaf(ab.y, v1.y, a1[tt].y);
        a1[tt].z = fmaf(ab.z, v1.z, a1[tt].z);
        a1[tt].w = fmaf(ab.w, v1.w, a1[tt].w);
      }
    }
  }
  #pragma unroll
  for (int tt = 0; tt < 8; tt++) {
    lg[tt*8 + tg][hkg*2 + 0] = a0[tt].x + a0[tt].y + a0[tt].z + a0[tt].w;
    lg[tt*8 + tg][hkg*2 + 1] = a1[tt].x + a1[tt].y + a1[tt].z + a1[tt].w;
  }
  __syncthreads();

  {
    int t = tid >> 2, hh = tid & 3;
    float* row = &lg[t][hh*16];
    float m = row[0];
    #pragma unroll
    for (int k2 = 1; k2 < 16; k2++) m = fmaxf(m, row[k2]);
    float ex[16]; float s = 0.f;
    #pragma unroll
    for (int k2 = 0; k2 < 16; k2++) { ex[k2] = expf(row[k2]-m); s += ex[k2]; }
    float w = pdf_l[e*4 + hh] / s;
    #pragma unroll
    for (int k2 = 0; k2 < 16; k2++) row[k2] = ex[k2]*w;
  }
  __syncthreads();

  #pragma unroll
  for (int q = 0; q < 4; q++) {
    int idx = q*256 + tid;
    int t = idx >> 4, k2 = idx & 15;
    float s = lg[t][0*16+k2] + lg[t][1*16+k2] + lg[t][2*16+k2] + lg[t][3*16+k2];
    atomicAdd(alpha_pi + ((size_t)t*BB + n)*AA + k2, s);
  }
}

extern "C" void kernel_launch(void* const* d_in, const int* in_sizes, int n_in,
                              void* d_out, int out_size, void* d_ws, size_t ws_size,
                              hipStream_t stream) {
  const float* lpo   = (const float*)d_in[0];
  const float* lpu   = (const float*)d_in[1];
  const float* value = (const float*)d_in[2];
  const float* b     = (const float*)d_in[3];
  const float* u     = (const float*)d_in[4];
  const float* v     = (const float*)d_in[5];
  const float* tau   = (const float*)d_in[6];
  float* out = (float*)d_out;
  float* ws  = (float*)d_ws;

  float* Tr  = ws + WS_TR;
  float* aT  = ws + WS_AT;
  float* pdf = ws + WS_PDF;
  float* X0  = ws + WS_X0;
  float* X1  = ws + WS_X1;
  float* X2  = ws + WS_X2;
  unsigned* bar = (unsigned*)(ws + WS_BAR);
  float* Gb  = ws + WS_G;

  float* alpha_b  = out;
  float* alpha_pi = out + (size_t)TT*BB*SS;

  hipLaunchKernelGGL(k_trans2,  dim3(512), dim3(256), 0, stream, u, v, Tr);
  hipLaunchKernelGGL(k_alpha_a, dim3(16),  dim3(256), 0, stream, lpu, aT);
  hipLaunchKernelGGL(k_taupdf,  dim3(1),   dim3(64),  0, stream, tau, pdf);
  hipLaunchKernelGGL(k_zero,    dim3(256), dim3(256), 0, stream, X1, X2, bar, Gb, alpha_pi);

  void* args[10];
  args[0] = (void*)&Tr;  args[1] = (void*)&aT;  args[2] = (void*)&lpo;
  args[3] = (void*)&b;   args[4] = (void*)&X0;  args[5] = (void*)&X1;
  args[6] = (void*)&X2;  args[7] = (void*)&Gb;  args[8] = (void*)&alpha_b;
  args[9] = (void*)&bar;
  hipLaunchCooperativeKernel(k_scan, dim3(256), dim3(512), args, 0, stream);

  hipLaunchKernelGGL(k_lastbel, dim3(64), dim3(512), 0, stream, X1, lpo, alpha_b);
  hipLaunchKernelGGL(k_pi, dim3(512), dim3(256), 0, stream, alpha_b, value, pdf, alpha_pi);
}